// Round 3
// baseline (82.826 us; speedup 1.0000x reference)
//
#include <hip/hip_runtime.h>

// ChamferLoss: B=4, N=M=8192, D=3, fp32. Scalar out.
// MFMA split-f16 (validated EXACT r6-r18): A = refs (LDS), B = queries (regs),
// in-lane min3 tree, VGPR-dest asm MFMA (r13), 2+2 grouped hazard tail (r15),
// __launch_bounds__(256,8) occupancy band (r16).
// r17 LESSON: per-block agent-scope release/acquire = buffer_wbl2+buffer_inv
// in all 2048 blocks -> TCC serialization, 3x regression. No per-block fences.
// r18: presplit kernel (one-shot frag packing) - wash, because staging still
// went through a VGPR round-trip. Timed region includes the harness's 268MB
// ws re-poison (~42us fixed); controllable budget ~37us.
// r19: cash in the presplit layout: (a) afrag staged via
// __builtin_amdgcn_global_load_lds width=16 (linear LDS image, wave-uniform
// base + lane*16 - no VGPR round-trip, no ds_writes, ~zero prologue VALU);
// (b) 2 qblock passes per block (grid 2048->1024): staged slice reused for a
// second query pass -> staging burst halved 33->17MB, half the sync convoys.
// d-pair asm kept at 2 MFMAs (4-fused would put 64 d-VGPRs live and bust the
// <=64-VGPR/8-wave band -> spill).

#define BATCH   4
#define NPTS    8192
#define TPB     256
#define CSLICE  512                  // ref points per block (LDS slice)
#define QT      4                    // query tiles (32 cols) per wave
#define QBLK    (4 * QT * 32)        // 512 queries per block-pass
#define MT      (CSLICE / 32)        // 16 ref tiles per slice
#define SLICES  (NPTS / CSLICE)      // 16
#define QBLKS   (NPTS / QBLK)        // 16
#define QPASS   2                    // qblocks served per block
#define FR_PER_SB 16384              // h8 frags per (side,b): 8192 pts * 2

typedef _Float16 h8   __attribute__((ext_vector_type(8)));
typedef float    f16v __attribute__((ext_vector_type(16)));

__device__ __forceinline__ void split16(float v, _Float16& hi, _Float16& lo) {
    hi = (_Float16)v;
    lo = (_Float16)(v - (float)hi);
}

__device__ __forceinline__ float tree16(const f16v& d) {
    float g0 = fminf(fminf(d[0],  d[1]),  d[2]);
    float g1 = fminf(fminf(d[3],  d[4]),  d[5]);
    float g2 = fminf(fminf(d[6],  d[7]),  d[8]);
    float g3 = fminf(fminf(d[9],  d[10]), d[11]);
    float g4 = fminf(fminf(d[12], d[13]), d[14]);
    float h0 = fminf(fminf(g0, g1), d[15]);
    float h1 = fminf(fminf(g2, g3), g4);
    return fminf(h0, h1);
}

// ---- one-shot fragment precompute (layout validated EXACT r17/r18) ----
__global__ __launch_bounds__(TPB) void chamfer_presplit(const float* __restrict__ xg,
                                                        const float* __restrict__ yg,
                                                        h8* __restrict__ aArr,
                                                        h8* __restrict__ bArr,
                                                        float* __restrict__ out) {
    const int tid = threadIdx.x;
    const int g   = blockIdx.x * TPB + tid;        // [0, BATCH*NPTS)
    if (blockIdx.x == 0 && tid == 0) out[0] = 0.0f;   // reduce runs after (stream order)
    const int b = g >> 13, i = g & (NPTS - 1);
#pragma unroll
    for (int s = 0; s < 2; ++s) {
        const float* p = (s ? yg : xg) + ((size_t)b * NPTS + i) * 3;
        float c0 = p[0], c1 = p[1], c2 = p[2];
        _Float16 h0, l0, h1, l1, h2, l2, nh, nl, H0, L0, H1, L1, H2, L2;
        split16(c0, h0, l0);                       // a-side: RAW coords
        split16(c1, h1, l1);
        split16(c2, h2, l2);
        split16(fmaf(c0, c0, fmaf(c1, c1, c2 * c2)), nh, nl);  // |p|^2
        split16(-2.0f * c0, H0, L0);               // b-side: -2q, split AFTER scaling
        split16(-2.0f * c1, H1, L1);
        split16(-2.0f * c2, H2, L2);
        const size_t base = (size_t)(s * BATCH + b) * FR_PER_SB;
        aArr[base + (i >> 5) * 64 + (i & 31)]      =
            (h8){h0, h1, h2, l0, l1, l2, h0, h1};                           // k0..7
        aArr[base + (i >> 5) * 64 + 32 + (i & 31)] =
            (h8){h2, nh, nl, (_Float16)1.0f, (_Float16)1.0f,
                 (_Float16)0.0f, (_Float16)0.0f, (_Float16)0.0f};           // k8..15
        bArr[base + i * 2]     =
            (h8){H0, H1, H2, H0, H1, H2, L0, L1};                           // k0..7
        bArr[base + i * 2 + 1] =
            (h8){L2, (_Float16)1.0f, (_Float16)1.0f, nh, nl,
                 (_Float16)0.0f, (_Float16)0.0f, (_Float16)0.0f};           // k8..15
    }
}

__global__ __launch_bounds__(TPB, 8) void chamfer_mfma(const h8* __restrict__ aArr,
                                                       const h8* __restrict__ bArr,
                                                       float* __restrict__ partial) {
    __shared__ h8 afrag[CSLICE * 2];          // 16 KB, de-interleaved (conflict-free)

    const int tid    = threadIdx.x;
    const int qpair  = blockIdx.x;            // [0,8): serves qblocks 2*qpair..+1
    const int slice  = blockIdx.y & (SLICES - 1);
    const int b      = blockIdx.y >> 4;       // SLICES == 16
    const int dir    = blockIdx.z;
    const int lane   = tid & 63, wave = tid >> 6;
    const int col    = lane & 31, hv = lane >> 5;

    const int sa = dir ? 0 : 1;               // ref side:   dir0 -> y, dir1 -> x
    const int sb = dir ? 1 : 0;               // query side

    // ---- stage ref A-frags: direct global->LDS DMA of the precomputed image ----
    // LDS dest is linear (wave-uniform base + lane*16): presplit layout makes
    // this legal. No VGPR round-trip, no ds_writes.
    const h8* asrc = aArr + (size_t)(sa * BATCH + b) * FR_PER_SB + slice * (CSLICE * 2);
#pragma unroll
    for (int i2 = 0; i2 < (CSLICE * 2) / TPB; ++i2) {          // 4x 16B per thread
        __builtin_amdgcn_global_load_lds(
            (const __attribute__((address_space(1))) unsigned int*)(asrc + tid + i2 * TPB),
            (__attribute__((address_space(3))) unsigned int*)(&afrag[tid + i2 * TPB]),
            16, 0, 0);
    }
    const h8* bsrc = bArr + (size_t)(sb * BATCH + b) * FR_PER_SB;
    __syncthreads();                          // drains vmcnt incl. load_lds

    for (int qp = 0; qp < QPASS; ++qp) {
        const int qblock = qpair * QPASS + qp;

        // ---- query B-frags: one 16B load per tile (hv-selected half) ----
        h8 bq[QT];
#pragma unroll
        for (int t = 0; t < QT; ++t) {
            const int qi = qblock * QBLK + (wave * QT + t) * 32 + col;
            bq[t] = bsrc[qi * 2 + hv];
        }

        float cm[QT];
#pragma unroll
        for (int t = 0; t < QT; ++t) cm[t] = 3.0e38f;

        // ---- main loop: 1 A-frag read -> 2x (2 MFMAs + 2 trees) ----
        for (int mt = 0; mt < MT; ++mt) {
            const h8 ar = afrag[mt * 64 + lane];   // contiguous 16B/lane, conflict-free
            f16v d0, d1;
            asm("v_mfma_f32_32x32x16_f16 %0, %2, %3, 0\n\t"
                "v_mfma_f32_32x32x16_f16 %1, %2, %4, 0\n\t"
                "s_nop 7\n\t"
                "s_nop 7"
                : "=v"(d0), "=v"(d1)
                : "v"(ar), "v"(bq[0]), "v"(bq[1]));
            cm[0] = fminf(cm[0], tree16(d0));
            cm[1] = fminf(cm[1], tree16(d1));

            f16v d2, d3;
            asm("v_mfma_f32_32x32x16_f16 %0, %2, %3, 0\n\t"
                "v_mfma_f32_32x32x16_f16 %1, %2, %4, 0\n\t"
                "s_nop 7\n\t"
                "s_nop 7"
                : "=v"(d2), "=v"(d3)
                : "v"(ar), "v"(bq[2]), "v"(bq[3]));
            cm[2] = fminf(cm[2], tree16(d2));
            cm[3] = fminf(cm[3], tree16(d3));
        }

        // ---- epilogue: one xor32 per accumulator, coalesced stores ----
        float* pp = partial + ((size_t)(dir * BATCH + b) * SLICES + slice) * NPTS
                            + qblock * QBLK;
#pragma unroll
        for (int t = 0; t < QT; ++t) {
            cm[t] = fminf(cm[t], __shfl_xor(cm[t], 32, 64));   // hv-partner rows
            if (hv == 0)
                pp[(wave * QT + t) * 32 + col] = cm[t];        // 32 lanes, 128B coalesced
        }
        // afrag is read-only after the first sync: no barrier between passes
    }
}

__global__ __launch_bounds__(TPB) void chamfer_reduce(const float* __restrict__ partial,
                                                      float* __restrict__ out) {
    const int tid = threadIdx.x;
    const int g   = blockIdx.x * TPB + tid;   // [0, 2*BATCH*NPTS)
    const int db  = g >> 13;                  // (dir*BATCH + b)
    const int n   = g & (NPTS - 1);

    const float* p = partial + (size_t)db * SLICES * NPTS + n;
    float v = 3.0e38f;
#pragma unroll
    for (int s = 0; s < SLICES; ++s)
        v = fminf(v, p[(size_t)s * NPTS]);    // coalesced across threads

    float w = v;
#pragma unroll
    for (int off = 32; off > 0; off >>= 1)
        w += __shfl_down(w, off, 64);
    __shared__ float ss[TPB / 64];
    if ((tid & 63) == 0) ss[tid >> 6] = w;
    __syncthreads();
    if (tid == 0)
        atomicAdd(out, (ss[0] + ss[1] + ss[2] + ss[3]) * (1.0f / (float)(BATCH * NPTS)));
}

extern "C" void kernel_launch(void* const* d_in, const int* in_sizes, int n_in,
                              void* d_out, int out_size, void* d_ws, size_t ws_size,
                              hipStream_t stream) {
    const float* x = (const float*)d_in[0];
    const float* y = (const float*)d_in[1];
    float* out = (float*)d_out;
    char* ws = (char*)d_ws;
    float* partial = (float*)ws;                    // 4 MB
    h8*    aArr    = (h8*)(ws + (4u << 20));        // 2 MB (2 sides x 4 b x 16K h8)
    h8*    bArr    = (h8*)(ws + (6u << 20));        // 2 MB

    chamfer_presplit<<<dim3(BATCH * NPTS / TPB), TPB, 0, stream>>>(x, y, aArr, bArr, out);
    chamfer_mfma<<<dim3(QBLKS / QPASS, BATCH * SLICES, 2), TPB, 0, stream>>>(aArr, bArr,
                                                                             partial);
    chamfer_reduce<<<dim3(2 * BATCH * NPTS / TPB), TPB, 0, stream>>>(partial, out);
}

// Round 4
// 75.461 us; speedup vs baseline: 1.0976x; 1.0976x over previous
//
#include <hip/hip_runtime.h>

// ChamferLoss: B=4, N=M=8192, D=3, fp32. Scalar out.
// MFMA split-f16 (validated EXACT r6-r19): A = refs (LDS), B = queries (regs),
// in-lane min3 tree, VGPR-dest asm MFMA (r13).
// LEDGER: r0(2+2 asm, 8-wave band)=77.4 | r17 fused-reduce fence=149 (NEVER
// per-block agent fences) | r18 presplit=80.1 | r19 presplit+gload_lds+
// QPASS2=82.8. Presplit arc net-negative: prologue VALU was already hidden;
// extra dispatch costs more than it saves. Reverted to r0 structure.
// r20 (this): single delta vs r0 - the untested ILP/occupancy quadrant.
// mfma loop runs at ~25% of its 6.8us MFMA-pipe bound; the 2+2 grouping
// forces [2 MFMA -> 16 nop cyc -> dependent tree] serial per group (d-reg
// reuse blocks pipelining). Fix: ONE asm block issuing all 4 MFMAs
// back-to-back (pipe-serialized ~128cyc = issue shadow for other waves'
// trees), then 4 trees. d-live = 64 VGPR -> 65-128 band (m69: 4 waves/SIMD),
// __launch_bounds__(256,4). Hazard: first d0 read >= mfma1-3 issue + 16
// nops after d0 issue >> r15's empirically-safe ~34cyc margin.
// Failure signature: VGPR spill (FETCH/WRITE jump) or >=77us -> revert r0.

#define BATCH   4
#define NPTS    8192
#define TPB     256
#define CSLICE  512                  // ref points per block (LDS slice)
#define QT      4                    // query tiles (32 cols) per wave
#define QBLK    (4 * QT * 32)        // 512 queries per block
#define MT      (CSLICE / 32)        // 16 ref tiles per slice
#define SLICES  (NPTS / CSLICE)      // 16
#define QBLKS   (NPTS / QBLK)        // 16

typedef _Float16 h8   __attribute__((ext_vector_type(8)));
typedef float    f16v __attribute__((ext_vector_type(16)));

__device__ __forceinline__ void split16(float v, _Float16& hi, _Float16& lo) {
    hi = (_Float16)v;
    lo = (_Float16)(v - (float)hi);
}

__device__ __forceinline__ float tree16(const f16v& d) {
    float g0 = fminf(fminf(d[0],  d[1]),  d[2]);
    float g1 = fminf(fminf(d[3],  d[4]),  d[5]);
    float g2 = fminf(fminf(d[6],  d[7]),  d[8]);
    float g3 = fminf(fminf(d[9],  d[10]), d[11]);
    float g4 = fminf(fminf(d[12], d[13]), d[14]);
    float h0 = fminf(fminf(g0, g1), d[15]);
    float h1 = fminf(fminf(g2, g3), g4);
    return fminf(h0, h1);
}

__global__ __launch_bounds__(TPB, 4) void chamfer_mfma(const float* __restrict__ xg,
                                                       const float* __restrict__ yg,
                                                       float* __restrict__ partial,
                                                       float* __restrict__ out) {
    __shared__ h8 afrag[CSLICE * 2];          // 16 KB, de-interleaved (conflict-free)

    const int tid    = threadIdx.x;
    const int qblock = blockIdx.x;            // [0,16)
    const int slice  = blockIdx.y & (SLICES - 1);
    const int b      = blockIdx.y >> 4;       // SLICES == 16
    const int dir    = blockIdx.z;
    const int lane   = tid & 63, wave = tid >> 6;
    const int col    = lane & 31, hv = lane >> 5;

    if (tid == 0) out[0] = 0.0f;              // benign identical-value race;
                                              // reduce runs after via stream order
    const float* q = dir ? yg : xg;           // query side (cols, register B-frags)
    const float* r = dir ? xg : yg;           // reference side (rows, LDS A-frags)

    // ---- stage ref A-frags: 2 points per thread, de-interleaved layout ----
    const float* rbase = r + ((size_t)b * NPTS + slice * CSLICE) * 3;
#pragma unroll
    for (int i = 0; i < CSLICE / TPB; ++i) {
        const int p = tid + i * TPB;
        float r0 = rbase[p * 3 + 0], r1 = rbase[p * 3 + 1], r2 = rbase[p * 3 + 2];
        _Float16 h0, l0, h1, l1, h2, l2, rnh, rnl;
        split16(r0, h0, l0);                  // a-side: RAW coords
        split16(r1, h1, l1);
        split16(r2, h2, l2);
        split16(fmaf(r0, r0, fmaf(r1, r1, r2 * r2)), rnh, rnl);
        const int base = (p >> 5) * 64 + (p & 31);            // [tile][hv][row]
        afrag[base]      = (h8){h0, h1, h2, l0, l1, l2, h0, h1};            // k0..7
        afrag[base + 32] = (h8){h2, rnh, rnl, (_Float16)1.0f, (_Float16)1.0f,
                                (_Float16)0.0f, (_Float16)0.0f, (_Float16)0.0f}; // k8..15
    }

    // ---- query B-frags: QT col-tiles per wave, resident in registers ----
    h8 bq[QT];
#pragma unroll
    for (int t = 0; t < QT; ++t) {
        const int qi = qblock * QBLK + (wave * QT + t) * 32 + col;
        const float* qp = q + ((size_t)b * NPTS + qi) * 3;
        float x0 = qp[0], x1 = qp[1], x2 = qp[2];
        _Float16 H0, L0, H1, L1, H2, L2, qnh, qnl;
        split16(-2.0f * x0, H0, L0);          // b-side: -2q, split AFTER scaling
        split16(-2.0f * x1, H1, L1);
        split16(-2.0f * x2, H2, L2);
        split16(fmaf(x0, x0, fmaf(x1, x1, x2 * x2)), qnh, qnl);
        h8 b0 = {H0, H1, H2, H0, H1, H2, L0, L1};                           // k0..7
        h8 b1 = {L2, (_Float16)1.0f, (_Float16)1.0f, qnh, qnl,
                 (_Float16)0.0f, (_Float16)0.0f, (_Float16)0.0f};           // k8..15
        bq[t] = hv ? b1 : b0;
    }
    __syncthreads();

    float cm[QT];
#pragma unroll
    for (int t = 0; t < QT; ++t) cm[t] = 3.0e38f;

    // ---- main loop: 1 A-frag read -> 4 MFMAs back-to-back (pipe-serialized
    // ~128cyc issue shadow), then 4 independent trees. d0 read lands far past
    // the validated hazard margin (mfma1-3 issue + 16 nops). ----
    for (int mt = 0; mt < MT; ++mt) {
        const h8 ar = afrag[mt * 64 + lane];   // contiguous 16B/lane, conflict-free
        f16v d0, d1, d2, d3;
        asm("v_mfma_f32_32x32x16_f16 %0, %4, %5, 0\n\t"
            "v_mfma_f32_32x32x16_f16 %1, %4, %6, 0\n\t"
            "v_mfma_f32_32x32x16_f16 %2, %4, %7, 0\n\t"
            "v_mfma_f32_32x32x16_f16 %3, %4, %8, 0\n\t"
            "s_nop 7\n\t"
            "s_nop 7"
            : "=v"(d0), "=v"(d1), "=v"(d2), "=v"(d3)
            : "v"(ar), "v"(bq[0]), "v"(bq[1]), "v"(bq[2]), "v"(bq[3]));
        cm[0] = fminf(cm[0], tree16(d0));
        cm[1] = fminf(cm[1], tree16(d1));
        cm[2] = fminf(cm[2], tree16(d2));
        cm[3] = fminf(cm[3], tree16(d3));
    }

    // ---- epilogue: one xor32 per accumulator, coalesced stores ----
    float* pp = partial + ((size_t)(dir * BATCH + b) * SLICES + slice) * NPTS
                        + qblock * QBLK;
#pragma unroll
    for (int t = 0; t < QT; ++t) {
        cm[t] = fminf(cm[t], __shfl_xor(cm[t], 32, 64));   // hv-partner rows
        if (hv == 0)
            pp[(wave * QT + t) * 32 + col] = cm[t];        // 32 lanes, 128B coalesced
    }
}

__global__ __launch_bounds__(TPB) void chamfer_reduce(const float* __restrict__ partial,
                                                      float* __restrict__ out) {
    const int tid = threadIdx.x;
    const int g   = blockIdx.x * TPB + tid;   // [0, 2*BATCH*NPTS)
    const int db  = g >> 13;                  // (dir*BATCH + b)
    const int n   = g & (NPTS - 1);

    const float* p = partial + (size_t)db * SLICES * NPTS + n;
    float v = 3.0e38f;
#pragma unroll
    for (int s = 0; s < SLICES; ++s)
        v = fminf(v, p[(size_t)s * NPTS]);    // coalesced across threads

    float w = v;
#pragma unroll
    for (int off = 32; off > 0; off >>= 1)
        w += __shfl_down(w, off, 64);
    __shared__ float ss[TPB / 64];
    if ((tid & 63) == 0) ss[tid >> 6] = w;
    __syncthreads();
    if (tid == 0)
        atomicAdd(out, (ss[0] + ss[1] + ss[2] + ss[3]) * (1.0f / (float)(BATCH * NPTS)));
}

extern "C" void kernel_launch(void* const* d_in, const int* in_sizes, int n_in,
                              void* d_out, int out_size, void* d_ws, size_t ws_size,
                              hipStream_t stream) {
    const float* x = (const float*)d_in[0];
    const float* y = (const float*)d_in[1];
    float* out = (float*)d_out;
    float* partial = (float*)d_ws;            // 2*4*16*8192*4 = 4 MB

    chamfer_mfma<<<dim3(QBLKS, BATCH * SLICES, 2), TPB, 0, stream>>>(x, y, partial, out);
    chamfer_reduce<<<dim3(2 * BATCH * NPTS / TPB), TPB, 0, stream>>>(partial, out);
}